// Round 6
// baseline (193.517 us; speedup 1.0000x reference)
//
#include <hip/hip_runtime.h>
#include <hip/hip_bf16.h>

#define B_    4
#define C_    256
#define NTOK  2304
#define NH    8
#define DH    32

typedef short bf16x8 __attribute__((ext_vector_type(8)));
typedef short bf16x4 __attribute__((ext_vector_type(4)));
typedef float f32x4  __attribute__((ext_vector_type(4)));

// round-to-nearest-even f32 -> bf16, finite inputs only (3 VALU ops)
__device__ __forceinline__ short rne_bf16(float f) {
    union { float f; unsigned u; } v; v.f = f;
    const unsigned r = v.u + 0x7fffu + ((v.u >> 16) & 1u);
    return (short)(r >> 16);
}
__device__ __forceinline__ unsigned pack2_bf16(float a, float b) {
    return (unsigned)(unsigned short)rne_bf16(a) | ((unsigned)(unsigned short)rne_bf16(b) << 16);
}
__device__ __forceinline__ float fast_exp2(float x) {
#if __has_builtin(__builtin_amdgcn_exp2f)
    return __builtin_amdgcn_exp2f(x);
#else
    return exp2f(x);
#endif
}

// ---------------------------------------------------------------------------
// Kernel 0: prep.  Blocks 0..575: transpose+convert x[b,c,n] -> xt[b,n,c] bf16.
// Blocks 576..639: convert w_qkv then w_proj to bf16.
// ---------------------------------------------------------------------------
__global__ __launch_bounds__(256) void prep_kernel(
    const float* __restrict__ x, const float* __restrict__ wq,
    const float* __restrict__ wp,
    short* __restrict__ xt, short* __restrict__ wqb, short* __restrict__ wpb)
{
    const int blk = blockIdx.x;
    const int t   = threadIdx.x;
    if (blk < 576) {
        const int b  = blk / 144;
        const int rem = blk % 144;
        const int n0 = (rem / 4) * 64;
        const int c0 = (rem % 4) * 64;
        __shared__ float tile[64][65];
        const float* xb = x + ((size_t)b * C_ + c0) * NTOK + n0;
        const int n = t & 63, cc = t >> 6;
        #pragma unroll
        for (int r = 0; r < 16; ++r)
            tile[cc + r * 4][n] = xb[(size_t)(cc + r * 4) * NTOK + n];
        __syncthreads();
        const int nr = t >> 2, cb = (t & 3) * 16;
        short* dst = xt + ((size_t)b * NTOK + n0 + nr) * C_ + c0 + cb;
        bf16x8 v0, v1;
        #pragma unroll
        for (int u = 0; u < 8; ++u) v0[u] = rne_bf16(tile[cb + u][nr]);
        #pragma unroll
        for (int u = 0; u < 8; ++u) v1[u] = rne_bf16(tile[cb + 8 + u][nr]);
        *(bf16x8*)dst = v0;
        *(bf16x8*)(dst + 8) = v1;
    } else {
        const int id = (blk - 576) * 256 + t;
        const int base = id * 16;
        #pragma unroll
        for (int u = 0; u < 4; ++u) {
            const int off = base + u * 4;
            float4 v; short* d;
            if (off < 196608) { v = *(const float4*)(wq + off); d = wqb + off; }
            else { v = *(const float4*)(wp + (off - 196608)); d = wpb + (off - 196608); }
            d[0] = rne_bf16(v.x); d[1] = rne_bf16(v.y);
            d[2] = rne_bf16(v.z); d[3] = rne_bf16(v.w);
        }
    }
}

// ---------------------------------------------------------------------------
// Kernel 1: QKV projection, MFMA.  One wave per 32x64 tile (3456 waves = 864
// blocks), direct global b128 fragment loads.  Epilogue assembles the tile in
// wave-private LDS, then fully-coalesced b128 global stores.
// q pre-scaled by dh^-0.5 * log2(e); q,k -> [B*h,N,dh]; v -> [B*h,dh,N].
// ---------------------------------------------------------------------------
__global__ __launch_bounds__(256) void qkv_mfma(
    const short* __restrict__ xt,   // [B][N][C] bf16
    const short* __restrict__ wqb,  // [768][256] bf16
    const float* __restrict__ bias, // [768] fp32
    short* __restrict__ qb, short* __restrict__ kb, short* __restrict__ vt)
{
    __shared__ short Es[4][2560];   // per-wave epilogue buffer
    const int wave = threadIdx.x >> 6;
    const int lane = threadIdx.x & 63;
    const int quad = lane >> 4, l16 = lane & 15;
    const int wid  = blockIdx.x * 4 + wave;   // 0..3455
    const int b    = wid / 864;
    const int rem  = wid % 864;
    const int mt = rem / 12, nt = rem % 12;
    const int m0 = mt * 32, j0 = nt * 64;

    const short* abase = xt + ((size_t)b * NTOK + m0 + l16) * C_ + quad * 8;
    const short* bbase = wqb + (size_t)(j0 + l16) * C_ + quad * 8;

    f32x4 acc[2][4] = {};
    for (int k0 = 0; k0 < C_; k0 += 32) {
        bf16x8 af[2], bfr[4];
        #pragma unroll
        for (int i = 0; i < 2; ++i)
            af[i] = *(const bf16x8*)(abase + (size_t)i * 16 * C_ + k0);
        #pragma unroll
        for (int j = 0; j < 4; ++j)
            bfr[j] = *(const bf16x8*)(bbase + (size_t)j * 16 * C_ + k0);
        #pragma unroll
        for (int i = 0; i < 2; ++i)
            #pragma unroll
            for (int j = 0; j < 4; ++j)
                acc[i][j] = __builtin_amdgcn_mfma_f32_16x16x32_bf16(af[i], bfr[j], acc[i][j], 0, 0, 0);
    }

    short* Ew = Es[wave];
    const int three = j0 >> 8;                 // wave-uniform: 0=q 1=k 2=v
    if (three < 2) {
        // layout Es[n(32)][stride 72]: scalar writes, b128 row reads
        const float sc = (three == 0) ? 0.25503486f : 1.0f;  // q: 32^-.5*log2e
        #pragma unroll
        for (int j = 0; j < 4; ++j) {
            const float bv = bias[j0 + j * 16 + l16];
            #pragma unroll
            for (int i = 0; i < 2; ++i)
                #pragma unroll
                for (int r = 0; r < 4; ++r) {
                    const int n_l = i * 16 + quad * 4 + r;
                    Ew[n_l * 72 + j * 16 + l16] = rne_bf16((acc[i][j][r] + bv) * sc);
                }
        }
        // wave-private LDS: no barrier needed (verified pattern r4/r5)
        const int n_l = lane & 31, hh = lane >> 5;
        const int head = ((j0 + hh * 32) >> 5) & 7;
        short* dst = ((three == 0) ? qb : kb)
                   + ((size_t)(b * NH + head) * NTOK + m0 + n_l) * DH;
        #pragma unroll
        for (int s = 0; s < 4; ++s)
            *(bf16x8*)(dst + s * 8) = *(const bf16x8*)&Ew[n_l * 72 + hh * 32 + s * 8];
    } else {
        // layout Es[j(64)][stride 40]: packed b32 writes, b128 row reads
        #pragma unroll
        for (int j = 0; j < 4; ++j) {
            const float bv = bias[j0 + j * 16 + l16];
            const int j_l = j * 16 + l16;
            #pragma unroll
            for (int i = 0; i < 2; ++i) {
                const int nb = i * 16 + quad * 4;
                *(unsigned*)&Ew[j_l * 40 + nb] =
                    pack2_bf16(acc[i][j][0] + bv, acc[i][j][1] + bv);
                *(unsigned*)&Ew[j_l * 40 + nb + 2] =
                    pack2_bf16(acc[i][j][2] + bv, acc[i][j][3] + bv);
            }
        }
        #pragma unroll
        for (int p = 0; p < 4; ++p) {
            const int j_r = p * 16 + (lane >> 2);
            const int seg = (lane & 3) * 8;
            const int head = ((j0 + j_r) >> 5) & 7;
            const int d    = j_r & 31;
            *(bf16x8*)(vt + ((size_t)(b * NH + head) * DH + d) * NTOK + m0 + seg) =
                *(const bf16x8*)&Ew[j_r * 40 + seg];
        }
    }
}

// ---------------------------------------------------------------------------
// Kernel 2: MFMA flash attention, max-free exp2 softmax (q pre-scaled by
// log2e/sqrt(dh); scores bounded so fp32 sums are safe).  block 256 (4 waves
// x 16 q-rows), grid (36,32).  128-key tiles: 8 QK MFMAs -> exp2 -> P in
// wave-private LDS -> 8 PV MFMAs vs V^T tile.  18 barrier pairs total.
// ---------------------------------------------------------------------------
__global__ __launch_bounds__(256) void attn_kernel(
    const short* __restrict__ qg,
    const short* __restrict__ kg,
    const short* __restrict__ vg,
    short* __restrict__ ob)      // [B*h][N][dh] bf16
{
    const int bh   = blockIdx.y;
    const int q0   = blockIdx.x * 64;
    const int t    = threadIdx.x;
    const int wave = t >> 6;
    const int lane = t & 63;
    const int quad = lane >> 4;
    const int l16  = lane & 15;

    __shared__ short Ks[128][40];     // K tile  [j][d]   (stride 80B: 16B-mult)
    __shared__ short Vt[32][168];     // V^T tile [d][j]  (stride 336B: 16B-mult)
    __shared__ short Ps[4][16][140];  // per-wave P [i][j] (stride 280B: 2-way banks)

    const short* kbase = kg + (size_t)bh * NTOK * DH;
    const short* vbase = vg + (size_t)bh * DH * NTOK;

    const short* qptr = qg + ((size_t)bh * NTOK + q0 + wave * 16 + l16) * DH + quad * 8;
    const bf16x8 qf = *(const bf16x8*)qptr;

    f32x4 Oc0 = {0.f, 0.f, 0.f, 0.f};
    f32x4 Oc1 = {0.f, 0.f, 0.f, 0.f};
    float lpart[4] = {0.f, 0.f, 0.f, 0.f};

    for (int kt = 0; kt < NTOK; kt += 128) {
        // stage K (128x32) and V^T (32x128); fully coalesced 16B chunks
        #pragma unroll
        for (int u = 0; u < 2; ++u) {
            const int chunk = u * 256 + t;           // 0..511
            const int krow = chunk >> 2, kseg = chunk & 3;
            *(bf16x8*)&Ks[krow][kseg * 8] =
                *(const bf16x8*)(kbase + (size_t)(kt + krow) * DH + kseg * 8);
            const int vr = chunk >> 4, vs = chunk & 15;
            *(bf16x8*)&Vt[vr][vs * 8] =
                *(const bf16x8*)(vbase + (size_t)vr * NTOK + kt + vs * 8);
        }
        __syncthreads();

        // QK^T: S[jt][r] -> score(row=quad*4+r, col=jt*16+l16)
        f32x4 S[8];
        #pragma unroll
        for (int jt = 0; jt < 8; ++jt) {
            const bf16x8 kf = *(const bf16x8*)&Ks[jt * 16 + l16][quad * 8];
            f32x4 z = {0.f, 0.f, 0.f, 0.f};
            S[jt] = __builtin_amdgcn_mfma_f32_16x16x32_bf16(qf, kf, z, 0, 0, 0);
        }

        // p = 2^s (log2e folded into q), park in wave-private LDS A-layout
        #pragma unroll
        for (int jt = 0; jt < 8; ++jt) {
            #pragma unroll
            for (int r = 0; r < 4; ++r) {
                const float p = fast_exp2(S[jt][r]);
                lpart[r] += p;
                Ps[wave][quad * 4 + r][jt * 16 + l16] = rne_bf16(p);
            }
        }

        // PV: O[row][d] += P[row][j] * V[j][d]
        #pragma unroll
        for (int jc = 0; jc < 4; ++jc) {
            const bf16x4 p0 = *(const bf16x4*)&Ps[wave][l16][jc * 32 + quad * 8];
            const bf16x4 p1 = *(const bf16x4*)&Ps[wave][l16][jc * 32 + quad * 8 + 4];
            bf16x8 af;
            af[0] = p0[0]; af[1] = p0[1]; af[2] = p0[2]; af[3] = p0[3];
            af[4] = p1[0]; af[5] = p1[1]; af[6] = p1[2]; af[7] = p1[3];
            const bf16x8 b0 = *(const bf16x8*)&Vt[l16][jc * 32 + quad * 8];
            const bf16x8 b1 = *(const bf16x8*)&Vt[16 + l16][jc * 32 + quad * 8];
            Oc0 = __builtin_amdgcn_mfma_f32_16x16x32_bf16(af, b0, Oc0, 0, 0, 0);
            Oc1 = __builtin_amdgcn_mfma_f32_16x16x32_bf16(af, b1, Oc1, 0, 0, 0);
        }
        __syncthreads();
    }

    // column-group sum of l, then normalized bf16 store
    #pragma unroll
    for (int off = 1; off < 16; off <<= 1) {
        #pragma unroll
        for (int r = 0; r < 4; ++r)
            lpart[r] += __shfl_xor(lpart[r], off, 64);
    }
    short* obase = ob + ((size_t)bh * NTOK + q0 + wave * 16 + quad * 4) * DH + l16;
    #pragma unroll
    for (int r = 0; r < 4; ++r) {
        const float inv = 1.f / lpart[r];
        obase[(size_t)r * DH]      = rne_bf16(Oc0[r] * inv);
        obase[(size_t)r * DH + 16] = rne_bf16(Oc1[r] * inv);
    }
}

// ---------------------------------------------------------------------------
// Kernel 3: output projection, MFMA.  One wave per 32x64 tile (1152 waves =
// 288 blocks).  Epilogue via wave-private LDS -> 128B-contiguous b128 stores.
// ---------------------------------------------------------------------------
__global__ __launch_bounds__(256) void proj_mfma(
    const short* __restrict__ ab,   // [B*8][N][32] bf16
    const short* __restrict__ wpb,  // [256][256] bf16
    const float* __restrict__ bias, // [256] fp32
    float* __restrict__ out)        // [B][256][2304] fp32
{
    __shared__ float Ep[4][2304];   // per-wave [c(64)][stride 36] floats
    const int wave = threadIdx.x >> 6;
    const int lane = threadIdx.x & 63;
    const int quad = lane >> 4, l16 = lane & 15;
    const int wid  = blockIdx.x * 4 + wave;   // 0..1151
    const int b    = wid / 288;
    const int rem  = wid % 288;
    const int mt = rem / 4, ct = rem % 4;
    const int m0 = mt * 32, c0 = ct * 64;

    const short* bbase = wpb + (size_t)(c0 + l16) * C_ + quad * 8;

    f32x4 acc[2][4] = {};
    for (int kt = 0; kt < 8; ++kt) {            // k0 = kt*32, head = kt
        const short* abase = ab + ((size_t)(b * NH + kt) * NTOK + m0 + l16) * DH + quad * 8;
        bf16x8 af[2], bfr[4];
        #pragma unroll
        for (int i = 0; i < 2; ++i)
            af[i] = *(const bf16x8*)(abase + (size_t)i * 16 * DH);
        #pragma unroll
        for (int j = 0; j < 4; ++j)
            bfr[j] = *(const bf16x8*)(bbase + (size_t)j * 16 * C_ + kt * 32);
        #pragma unroll
        for (int i = 0; i < 2; ++i)
            #pragma unroll
            for (int j = 0; j < 4; ++j)
                acc[i][j] = __builtin_amdgcn_mfma_f32_16x16x32_bf16(af[i], bfr[j], acc[i][j], 0, 0, 0);
    }

    float* Ew = Ep[wave];
    #pragma unroll
    for (int j = 0; j < 4; ++j) {
        const int j_l = j * 16 + l16;
        const float bv = bias[c0 + j_l];
        #pragma unroll
        for (int i = 0; i < 2; ++i) {
            f32x4 st = {acc[i][j][0] + bv, acc[i][j][1] + bv,
                        acc[i][j][2] + bv, acc[i][j][3] + bv};
            *(f32x4*)&Ew[j_l * 36 + i * 16 + quad * 4] = st;
        }
    }
    // wave-private LDS: no barrier needed
    #pragma unroll
    for (int p = 0; p < 8; ++p) {
        const int c_r = p * 8 + (lane >> 3);
        const int seg = (lane & 7) * 4;
        *(float4*)(out + ((size_t)b * C_ + c0 + c_r) * NTOK + m0 + seg) =
            *(const float4*)&Ew[c_r * 36 + seg];
    }
}

// ---------------------------------------------------------------------------
extern "C" void kernel_launch(void* const* d_in, const int* in_sizes, int n_in,
                              void* d_out, int out_size, void* d_ws, size_t ws_size,
                              hipStream_t stream) {
    const float* x      = (const float*)d_in[0];
    const float* w_qkv  = (const float*)d_in[1];
    const float* b_qkv  = (const float*)d_in[2];
    const float* w_proj = (const float*)d_in[3];
    const float* b_proj = (const float*)d_in[4];
    float* out = (float*)d_out;

    const size_t SZ = (size_t)B_ * NH * NTOK * DH;   // 2359296
    short* xt  = (short*)d_ws;            // [B][N][C]
    short* wqb = xt + SZ;                 // [768][256]
    short* wpb = wqb + 196608;            // [256][256]
    short* qb  = wpb + 65536;
    short* kb  = qb + SZ;
    short* vt  = kb + SZ;
    short* abf = vt + SZ;

    prep_kernel<<<640, 256, 0, stream>>>(x, w_qkv, w_proj, xt, wqb, wpb);
    qkv_mfma<<<864, 256, 0, stream>>>(xt, wqb, b_qkv, qb, kb, vt);
    attn_kernel<<<dim3(36, 32), 256, 0, stream>>>(qb, kb, vt, abf);
    proj_mfma<<<288, 256, 0, stream>>>(abf, wpb, b_proj, out);
}

// Round 7
// 173.415 us; speedup vs baseline: 1.1159x; 1.1159x over previous
//
#include <hip/hip_runtime.h>
#include <hip/hip_bf16.h>

#define B_    4
#define C_    256
#define NTOK  2304
#define NH    8
#define DH    32

typedef short bf16x8 __attribute__((ext_vector_type(8)));
typedef short bf16x4 __attribute__((ext_vector_type(4)));
typedef float f32x4  __attribute__((ext_vector_type(4)));

// round-to-nearest-even f32 -> bf16, finite inputs only (3 VALU ops)
__device__ __forceinline__ short rne_bf16(float f) {
    union { float f; unsigned u; } v; v.f = f;
    const unsigned r = v.u + 0x7fffu + ((v.u >> 16) & 1u);
    return (short)(r >> 16);
}
__device__ __forceinline__ unsigned pack2_bf16(float a, float b) {
    return (unsigned)(unsigned short)rne_bf16(a) | ((unsigned)(unsigned short)rne_bf16(b) << 16);
}
__device__ __forceinline__ float fast_exp2(float x) {
#if __has_builtin(__builtin_amdgcn_exp2f)
    return __builtin_amdgcn_exp2f(x);
#else
    return exp2f(x);
#endif
}

// ---------------------------------------------------------------------------
// Kernel 0: prep.  Blocks 0..575: transpose+convert x[b,c,n] -> xt[b,n,c] bf16.
// Blocks 576..639: convert w_qkv then w_proj to bf16.
// ---------------------------------------------------------------------------
__global__ __launch_bounds__(256) void prep_kernel(
    const float* __restrict__ x, const float* __restrict__ wq,
    const float* __restrict__ wp,
    short* __restrict__ xt, short* __restrict__ wqb, short* __restrict__ wpb)
{
    const int blk = blockIdx.x;
    const int t   = threadIdx.x;
    if (blk < 576) {
        const int b  = blk / 144;
        const int rem = blk % 144;
        const int n0 = (rem / 4) * 64;
        const int c0 = (rem % 4) * 64;
        __shared__ float tile[64][65];
        const float* xb = x + ((size_t)b * C_ + c0) * NTOK + n0;
        const int n = t & 63, cc = t >> 6;
        #pragma unroll
        for (int r = 0; r < 16; ++r)
            tile[cc + r * 4][n] = xb[(size_t)(cc + r * 4) * NTOK + n];
        __syncthreads();
        const int nr = t >> 2, cb = (t & 3) * 16;
        short* dst = xt + ((size_t)b * NTOK + n0 + nr) * C_ + c0 + cb;
        bf16x8 v0, v1;
        #pragma unroll
        for (int u = 0; u < 8; ++u) v0[u] = rne_bf16(tile[cb + u][nr]);
        #pragma unroll
        for (int u = 0; u < 8; ++u) v1[u] = rne_bf16(tile[cb + 8 + u][nr]);
        *(bf16x8*)dst = v0;
        *(bf16x8*)(dst + 8) = v1;
    } else {
        const int id = (blk - 576) * 256 + t;
        const int base = id * 16;
        #pragma unroll
        for (int u = 0; u < 4; ++u) {
            const int off = base + u * 4;
            float4 v; short* d;
            if (off < 196608) { v = *(const float4*)(wq + off); d = wqb + off; }
            else { v = *(const float4*)(wp + (off - 196608)); d = wpb + (off - 196608); }
            d[0] = rne_bf16(v.x); d[1] = rne_bf16(v.y);
            d[2] = rne_bf16(v.z); d[3] = rne_bf16(v.w);
        }
    }
}

// ---------------------------------------------------------------------------
// Kernel 1: QKV projection, MFMA.  One wave per 32x64 tile (3456 waves = 864
// blocks), direct global b128 fragment loads.  Epilogue via wave-private LDS,
// then fully-coalesced b128 global stores.
// q pre-scaled by dh^-0.5 * log2(e); q,k -> [B*h,N,dh]; v -> [B*h,dh,N].
// ---------------------------------------------------------------------------
__global__ __launch_bounds__(256) void qkv_mfma(
    const short* __restrict__ xt,   // [B][N][C] bf16
    const short* __restrict__ wqb,  // [768][256] bf16
    const float* __restrict__ bias, // [768] fp32
    short* __restrict__ qb, short* __restrict__ kb, short* __restrict__ vt)
{
    __shared__ short Es[4][2560];   // per-wave epilogue buffer
    const int wave = threadIdx.x >> 6;
    const int lane = threadIdx.x & 63;
    const int quad = lane >> 4, l16 = lane & 15;
    const int wid  = blockIdx.x * 4 + wave;   // 0..3455
    const int b    = wid / 864;
    const int rem  = wid % 864;
    const int mt = rem / 12, nt = rem % 12;
    const int m0 = mt * 32, j0 = nt * 64;

    const short* abase = xt + ((size_t)b * NTOK + m0 + l16) * C_ + quad * 8;
    const short* bbase = wqb + (size_t)(j0 + l16) * C_ + quad * 8;

    f32x4 acc[2][4] = {};
    for (int k0 = 0; k0 < C_; k0 += 32) {
        bf16x8 af[2], bfr[4];
        #pragma unroll
        for (int i = 0; i < 2; ++i)
            af[i] = *(const bf16x8*)(abase + (size_t)i * 16 * C_ + k0);
        #pragma unroll
        for (int j = 0; j < 4; ++j)
            bfr[j] = *(const bf16x8*)(bbase + (size_t)j * 16 * C_ + k0);
        #pragma unroll
        for (int i = 0; i < 2; ++i)
            #pragma unroll
            for (int j = 0; j < 4; ++j)
                acc[i][j] = __builtin_amdgcn_mfma_f32_16x16x32_bf16(af[i], bfr[j], acc[i][j], 0, 0, 0);
    }

    short* Ew = Es[wave];
    const int three = j0 >> 8;                 // wave-uniform: 0=q 1=k 2=v
    if (three < 2) {
        const float sc = (three == 0) ? 0.25503486f : 1.0f;  // q: 32^-.5*log2e
        #pragma unroll
        for (int j = 0; j < 4; ++j) {
            const float bv = bias[j0 + j * 16 + l16];
            #pragma unroll
            for (int i = 0; i < 2; ++i)
                #pragma unroll
                for (int r = 0; r < 4; ++r) {
                    const int n_l = i * 16 + quad * 4 + r;
                    Ew[n_l * 72 + j * 16 + l16] = rne_bf16((acc[i][j][r] + bv) * sc);
                }
        }
        const int n_l = lane & 31, hh = lane >> 5;
        const int head = ((j0 + hh * 32) >> 5) & 7;
        short* dst = ((three == 0) ? qb : kb)
                   + ((size_t)(b * NH + head) * NTOK + m0 + n_l) * DH;
        #pragma unroll
        for (int s = 0; s < 4; ++s)
            *(bf16x8*)(dst + s * 8) = *(const bf16x8*)&Ew[n_l * 72 + hh * 32 + s * 8];
    } else {
        #pragma unroll
        for (int j = 0; j < 4; ++j) {
            const float bv = bias[j0 + j * 16 + l16];
            const int j_l = j * 16 + l16;
            #pragma unroll
            for (int i = 0; i < 2; ++i) {
                const int nb = i * 16 + quad * 4;
                *(unsigned*)&Ew[j_l * 40 + nb] =
                    pack2_bf16(acc[i][j][0] + bv, acc[i][j][1] + bv);
                *(unsigned*)&Ew[j_l * 40 + nb + 2] =
                    pack2_bf16(acc[i][j][2] + bv, acc[i][j][3] + bv);
            }
        }
        #pragma unroll
        for (int p = 0; p < 4; ++p) {
            const int j_r = p * 16 + (lane >> 2);
            const int seg = (lane & 3) * 8;
            const int head = ((j0 + j_r) >> 5) & 7;
            const int d    = j_r & 31;
            *(bf16x8*)(vt + ((size_t)(b * NH + head) * DH + d) * NTOK + m0 + seg) =
                *(const bf16x8*)&Ew[j_r * 40 + seg];
        }
    }
}

// ---------------------------------------------------------------------------
// Kernel 2: MFMA flash attention, split-K over keys (max-free softmax =>
// partials add linearly).  grid (36, 32, 2): z = key half (1152 keys each).
// r5 structure: 64-key tiles, S[4], 18.4KB LDS, block 256 (4 waves x 16 q).
// Writes UNNORMALIZED O-partials (fp32) + l-partials; combine normalizes.
// ---------------------------------------------------------------------------
__global__ __launch_bounds__(256) void attn_kernel(
    const short* __restrict__ qg,
    const short* __restrict__ kg,
    const short* __restrict__ vg,
    float* __restrict__ po,      // [2][B*h][N][dh] fp32 unnormalized
    float* __restrict__ pl)      // [2][B*h][N] fp32 row sums
{
    const int bh   = blockIdx.y;
    const int q0   = blockIdx.x * 64;
    const int half = blockIdx.z;
    const int t    = threadIdx.x;
    const int wave = t >> 6;
    const int lane = t & 63;
    const int quad = lane >> 4;
    const int l16  = lane & 15;

    __shared__ short Ks[64][40];      // K tile  [j][d]
    __shared__ short Vt[32][72];      // V^T tile [d][j]
    __shared__ short Ps[4][16][68];   // per-wave P [i][j]

    const short* kbase = kg + (size_t)bh * NTOK * DH;
    const short* vbase = vg + (size_t)bh * DH * NTOK;

    const short* qptr = qg + ((size_t)bh * NTOK + q0 + wave * 16 + l16) * DH + quad * 8;
    const bf16x8 qf = *(const bf16x8*)qptr;

    f32x4 Oc0 = {0.f, 0.f, 0.f, 0.f};
    f32x4 Oc1 = {0.f, 0.f, 0.f, 0.f};
    float lpart[4] = {0.f, 0.f, 0.f, 0.f};

    const int kbeg = half * (NTOK / 2);
    const int kend = kbeg + (NTOK / 2);
    for (int kt = kbeg; kt < kend; kt += 64) {
        {
            const int kr = t >> 2, ksg = t & 3;
            *(bf16x8*)&Ks[kr][ksg * 8] =
                *(const bf16x8*)(kbase + (size_t)(kt + kr) * DH + ksg * 8);
            const int vr = t >> 3, vsg = t & 7;
            *(bf16x8*)&Vt[vr][vsg * 8] =
                *(const bf16x8*)(vbase + (size_t)vr * NTOK + kt + vsg * 8);
        }
        __syncthreads();

        // QK^T: S[jt][r] -> score(row=quad*4+r, col=jt*16+l16)
        f32x4 S[4];
        #pragma unroll
        for (int jt = 0; jt < 4; ++jt) {
            const bf16x8 kf = *(const bf16x8*)&Ks[jt * 16 + l16][quad * 8];
            f32x4 z = {0.f, 0.f, 0.f, 0.f};
            S[jt] = __builtin_amdgcn_mfma_f32_16x16x32_bf16(qf, kf, z, 0, 0, 0);
        }

        // p = 2^s (log2e folded into q), park in wave-private LDS A-layout
        #pragma unroll
        for (int jt = 0; jt < 4; ++jt) {
            #pragma unroll
            for (int r = 0; r < 4; ++r) {
                const float p = fast_exp2(S[jt][r]);
                lpart[r] += p;
                Ps[wave][quad * 4 + r][jt * 16 + l16] = rne_bf16(p);
            }
        }

        // PV: O[row][d] += P[row][j] * V[j][d]
        #pragma unroll
        for (int jc = 0; jc < 2; ++jc) {
            const bf16x4 p0 = *(const bf16x4*)&Ps[wave][l16][jc * 32 + quad * 8];
            const bf16x4 p1 = *(const bf16x4*)&Ps[wave][l16][jc * 32 + quad * 8 + 4];
            bf16x8 af;
            af[0] = p0[0]; af[1] = p0[1]; af[2] = p0[2]; af[3] = p0[3];
            af[4] = p1[0]; af[5] = p1[1]; af[6] = p1[2]; af[7] = p1[3];
            const bf16x8 b0 = *(const bf16x8*)&Vt[l16][jc * 32 + quad * 8];
            const bf16x8 b1 = *(const bf16x8*)&Vt[16 + l16][jc * 32 + quad * 8];
            Oc0 = __builtin_amdgcn_mfma_f32_16x16x32_bf16(af, b0, Oc0, 0, 0, 0);
            Oc1 = __builtin_amdgcn_mfma_f32_16x16x32_bf16(af, b1, Oc1, 0, 0, 0);
        }
        __syncthreads();
    }

    // row-sum l across the 16-lane column groups
    #pragma unroll
    for (int off = 1; off < 16; off <<= 1) {
        #pragma unroll
        for (int r = 0; r < 4; ++r)
            lpart[r] += __shfl_xor(lpart[r], off, 64);
    }

    const size_t rowbase = ((size_t)half * 32 + bh) * NTOK + q0 + wave * 16 + quad * 4;
    float* obase = po + rowbase * DH + l16;
    #pragma unroll
    for (int r = 0; r < 4; ++r) {
        obase[(size_t)r * DH]      = Oc0[r];
        obase[(size_t)r * DH + 16] = Oc1[r];
    }
    if (l16 == 0) {
        float* lb = pl + rowbase;
        #pragma unroll
        for (int r = 0; r < 4; ++r) lb[r] = lpart[r];
    }
}

// ---------------------------------------------------------------------------
// Kernel 2b: combine split-K partials:  O = (O0+O1)/(l0+l1), bf16 out.
// 73728 rows x 32 d; 4 threads/row (8 d each).  1152 blocks x 256.
// ---------------------------------------------------------------------------
__global__ __launch_bounds__(256) void combine_kernel(
    const float* __restrict__ po, const float* __restrict__ pl,
    short* __restrict__ ob)      // [B*h][N][dh] bf16
{
    const int gid = blockIdx.x * 256 + threadIdx.x;   // 0..294911
    const int row = gid >> 2;
    const int seg = (gid & 3) * 8;
    const float inv = 1.f / (pl[row] + pl[73728 + row]);
    const float* p0 = po + (size_t)row * DH + seg;
    const float* p1 = po + (size_t)73728 * DH + (size_t)row * DH + seg;
    f32x4 a0 = *(const f32x4*)p0;
    f32x4 a1 = *(const f32x4*)(p0 + 4);
    f32x4 b0 = *(const f32x4*)p1;
    f32x4 b1 = *(const f32x4*)(p1 + 4);
    bf16x8 o;
    #pragma unroll
    for (int u = 0; u < 4; ++u) o[u]     = rne_bf16((a0[u] + b0[u]) * inv);
    #pragma unroll
    for (int u = 0; u < 4; ++u) o[4 + u] = rne_bf16((a1[u] + b1[u]) * inv);
    *(bf16x8*)(ob + (size_t)row * DH + seg) = o;
}

// ---------------------------------------------------------------------------
// Kernel 3: output projection, MFMA.  One wave per 32x64 tile (1152 waves =
// 288 blocks).  Epilogue via wave-private LDS -> 128B-contiguous b128 stores.
// ---------------------------------------------------------------------------
__global__ __launch_bounds__(256) void proj_mfma(
    const short* __restrict__ ab,   // [B*8][N][32] bf16
    const short* __restrict__ wpb,  // [256][256] bf16
    const float* __restrict__ bias, // [256] fp32
    float* __restrict__ out)        // [B][256][2304] fp32
{
    __shared__ float Ep[4][2304];   // per-wave [c(64)][stride 36] floats
    const int wave = threadIdx.x >> 6;
    const int lane = threadIdx.x & 63;
    const int quad = lane >> 4, l16 = lane & 15;
    const int wid  = blockIdx.x * 4 + wave;   // 0..1151
    const int b    = wid / 288;
    const int rem  = wid % 288;
    const int mt = rem / 4, ct = rem % 4;
    const int m0 = mt * 32, c0 = ct * 64;

    const short* bbase = wpb + (size_t)(c0 + l16) * C_ + quad * 8;

    f32x4 acc[2][4] = {};
    for (int kt = 0; kt < 8; ++kt) {            // k0 = kt*32, head = kt
        const short* abase = ab + ((size_t)(b * NH + kt) * NTOK + m0 + l16) * DH + quad * 8;
        bf16x8 af[2], bfr[4];
        #pragma unroll
        for (int i = 0; i < 2; ++i)
            af[i] = *(const bf16x8*)(abase + (size_t)i * 16 * DH);
        #pragma unroll
        for (int j = 0; j < 4; ++j)
            bfr[j] = *(const bf16x8*)(bbase + (size_t)j * 16 * C_ + kt * 32);
        #pragma unroll
        for (int i = 0; i < 2; ++i)
            #pragma unroll
            for (int j = 0; j < 4; ++j)
                acc[i][j] = __builtin_amdgcn_mfma_f32_16x16x32_bf16(af[i], bfr[j], acc[i][j], 0, 0, 0);
    }

    float* Ew = Ep[wave];
    #pragma unroll
    for (int j = 0; j < 4; ++j) {
        const int j_l = j * 16 + l16;
        const float bv = bias[c0 + j_l];
        #pragma unroll
        for (int i = 0; i < 2; ++i) {
            f32x4 st = {acc[i][j][0] + bv, acc[i][j][1] + bv,
                        acc[i][j][2] + bv, acc[i][j][3] + bv};
            *(f32x4*)&Ew[j_l * 36 + i * 16 + quad * 4] = st;
        }
    }
    #pragma unroll
    for (int p = 0; p < 8; ++p) {
        const int c_r = p * 8 + (lane >> 3);
        const int seg = (lane & 7) * 4;
        *(float4*)(out + ((size_t)b * C_ + c0 + c_r) * NTOK + m0 + seg) =
            *(const float4*)&Ew[c_r * 36 + seg];
    }
}

// ---------------------------------------------------------------------------
extern "C" void kernel_launch(void* const* d_in, const int* in_sizes, int n_in,
                              void* d_out, int out_size, void* d_ws, size_t ws_size,
                              hipStream_t stream) {
    const float* x      = (const float*)d_in[0];
    const float* w_qkv  = (const float*)d_in[1];
    const float* b_qkv  = (const float*)d_in[2];
    const float* w_proj = (const float*)d_in[3];
    const float* b_proj = (const float*)d_in[4];
    float* out = (float*)d_out;

    const size_t SZ = (size_t)B_ * NH * NTOK * DH;   // 2359296
    short* xt  = (short*)d_ws;            // [B][N][C]
    short* wqb = xt + SZ;                 // [768][256]
    short* wpb = wqb + 196608;            // [256][256]
    short* qb  = wpb + 65536;
    short* kb  = qb + SZ;
    short* vt  = kb + SZ;
    short* abf = vt + SZ;
    float* po  = (float*)(abf + SZ);      // [2][32][2304][32] fp32
    float* pl  = po + 2 * SZ;             // [2][32][2304] fp32

    prep_kernel<<<640, 256, 0, stream>>>(x, w_qkv, w_proj, xt, wqb, wpb);
    qkv_mfma<<<864, 256, 0, stream>>>(xt, wqb, b_qkv, qb, kb, vt);
    attn_kernel<<<dim3(36, 32, 2), 256, 0, stream>>>(qb, kb, vt, po, pl);
    combine_kernel<<<1152, 256, 0, stream>>>(po, pl, abf);
    proj_mfma<<<288, 256, 0, stream>>>(abf, wpb, b_proj, out);
}